// Round 8
// baseline (1966.511 us; speedup 1.0000x reference)
//
#include <hip/hip_runtime.h>
#include <hip/hip_bf16.h>
#include <math.h>

#define BB 8
#define NN 2048
#define KK 10
#define QSPLIT 16                   // j-slices per row
#define JT 2                        // 64-col j-tiles per block (QSPLIT*JT*64 == NN)
#define EPSF 1e-5f
#define NEG_SLOPE 0.2f

// ---------------- xx[n] = sum_c x[n,c]^2 ----------------
__global__ void xx_kernel(const float* __restrict__ x, float* __restrict__ xx, int C) {
    int i = blockIdx.x * blockDim.x + threadIdx.x;
    if (i >= BB * NN) return;
    const float* row = x + (size_t)i * C;
    float s = 0.f;
    for (int c = 0; c < C; ++c) { float v = row[c]; s = fmaf(v, v, s); }
    xx[i] = s;
}

// ---------------- fused dist GEMM + exact top-10, row-per-thread ----------------
// Block = (j-slice of 128, i-tile of 64 rows, batch) -> 4096 blocks (16/CU).
// Micro-tile = 1 row x 16 cols per thread (row = tid&63, col-quarter = tid>>6):
// the 16 dist values of a thread live in registers FOR ONE ROW, so the top-10
// insert reads acc[] directly — no Ds LDS round-trip (round-7's 17KB + 8-way
// write conflicts + serial q==0 pointer-merge were the 310us pedestal).
// GEMM reads: A = stride-1 b32 (2-way, free), B = wave-uniform b128 broadcast.
// Accumulation order over k and the ((2a-xi)-xj) association are identical to
// round-3 dist_gemm -> bit-identical dist -> identical neighbor indices.
// Insert: unconditional branch-free stable sorted-insert, candidates ascend in
// j, value-only compare == (v desc, j asc) order.
// Merge: per-row 4 lists -> LDS (pitch 41: (41*row+c)%32 has no 8-row alias),
// each thread ranks its own 10 entries among the 40-union with packed
// (float-order, ~j) u64 keys — 300 independent compares, no dependent-load
// chain, no serial section — then scatter-writes rank<10 straight to global.
__global__ __launch_bounds__(256) void knn_fused_kernel(
    const float* __restrict__ x, const float* __restrict__ xx,
    float* __restrict__ hlv, int* __restrict__ hlj, int C) {
    int b = blockIdx.z;
    int i0 = blockIdx.y << 6;
    int qs = blockIdx.x;
    const float* xb = x + (size_t)b * NN * C;
    const float* xxb = xx + (size_t)b * NN;
    __shared__ union {
        struct { float As[16][68]; float Bs[16][68]; float Xs[64]; } g;
        struct { float Mv[64][41]; int Mj[64][41]; } m;
    } S;
    int tid = threadIdx.x;
    int row = tid & 63, q = tid >> 6;

    float lv[KK]; int lj[KK];
    #pragma unroll
    for (int e = 0; e < KK; ++e) { lv[e] = -INFINITY; lj[e] = 0x7fffffff; }

    float xi = xxb[i0 + row];

    for (int jt = 0; jt < JT; ++jt) {
        int j0 = ((qs * JT + jt) << 6);
        float acc[16];
        #pragma unroll
        for (int v = 0; v < 16; ++v) acc[v] = 0.f;
        for (int k0 = 0; k0 < C; k0 += 16) {
            #pragma unroll
            for (int l = tid; l < 1024; l += 256) {
                int r = l >> 4, c = l & 15;
                int kc = k0 + c;
                S.g.As[c][r] = (kc < C) ? xb[(size_t)(i0 + r) * C + kc] : 0.f;
                S.g.Bs[c][r] = (kc < C) ? xb[(size_t)(j0 + r) * C + kc] : 0.f;
            }
            if (k0 == 0 && tid < 64) S.g.Xs[tid] = xxb[j0 + tid];
            __syncthreads();
            #pragma unroll
            for (int kk = 0; kk < 16; ++kk) {
                float a = S.g.As[kk][row];
                #pragma unroll
                for (int v4 = 0; v4 < 4; ++v4) {
                    float4 b4 = *(const float4*)&S.g.Bs[kk][(q << 4) + (v4 << 2)];
                    acc[v4 * 4 + 0] = fmaf(a, b4.x, acc[v4 * 4 + 0]);
                    acc[v4 * 4 + 1] = fmaf(a, b4.y, acc[v4 * 4 + 1]);
                    acc[v4 * 4 + 2] = fmaf(a, b4.z, acc[v4 * 4 + 2]);
                    acc[v4 * 4 + 3] = fmaf(a, b4.w, acc[v4 * 4 + 3]);
                }
            }
            __syncthreads();
        }
        // corrections + branch-free stable insert (ascending j)
        #pragma unroll
        for (int v = 0; v < 16; ++v) {
            float cv = 2.f * acc[v] - xi - S.g.Xs[(q << 4) + v];
            int cj = j0 + (q << 4) + v;
            bool bt[KK];
            #pragma unroll
            for (int e = 0; e < KK; ++e) bt[e] = (cv > lv[e]);
            #pragma unroll
            for (int e = KK - 1; e > 0; --e) {
                lv[e] = bt[e] ? (bt[e - 1] ? lv[e - 1] : cv) : lv[e];
                lj[e] = bt[e] ? (bt[e - 1] ? lj[e - 1] : cj) : lj[e];
            }
            lv[0] = bt[0] ? cv : lv[0];
            lj[0] = bt[0] ? cj : lj[0];
        }
        __syncthreads();   // protect As/Bs/Xs from next tile's staging
    }

    // ---- parallel rank-based merge of the 4 per-row lists ----
    #pragma unroll
    for (int e = 0; e < KK; ++e) {
        S.m.Mv[row][q * KK + e] = lv[e];
        S.m.Mj[row][q * KK + e] = lj[e];
    }
    __syncthreads();
    unsigned long long mykey[KK];
    int rank[KK];
    #pragma unroll
    for (int e = 0; e < KK; ++e) {
        unsigned u = __float_as_uint(lv[e]);
        u = (u & 0x80000000u) ? ~u : (u | 0x80000000u);
        mykey[e] = ((unsigned long long)u << 32) | (unsigned)(~lj[e]);
        rank[e] = e;   // own-list predecessors (sorted, ties j-asc => key order)
    }
    for (int qo = 1; qo < 4; ++qo) {
        int q2 = (q + qo) & 3;
        #pragma unroll
        for (int f = 0; f < KK; ++f) {
            float ov = S.m.Mv[row][q2 * KK + f];
            int oj = S.m.Mj[row][q2 * KK + f];
            unsigned u = __float_as_uint(ov);
            u = (u & 0x80000000u) ? ~u : (u | 0x80000000u);
            unsigned long long okey = ((unsigned long long)u << 32) | (unsigned)(~oj);
            #pragma unroll
            for (int e = 0; e < KK; ++e) rank[e] += (okey > mykey[e]) ? 1 : 0;
        }
    }
    size_t base = (((size_t)b * NN + i0 + row) * QSPLIT + qs) * KK;
    #pragma unroll
    for (int e = 0; e < KK; ++e) {
        if (rank[e] < KK) {
            hlv[base + rank[e]] = lv[e];
            hlj[base + rank[e]] = lj[e];
        }
    }
}

// ---------------- final merge: 16 sorted slice-lists -> top-10 indices ----------------
// Slices cover disjoint j ranges; top-10 of union of slice top-10s is exact.
__global__ __launch_bounds__(64) void topk_merge_kernel(
    const float* __restrict__ hlv, const int* __restrict__ hlj,
    int* __restrict__ idxout) {
    int row = blockIdx.x * 64 + threadIdx.x;   // [0, BB*NN)
    size_t base = (size_t)row * (QSPLIT * KK);
    float hv[QSPLIT]; int hj[QSPLIT]; int p[QSPLIT];
    #pragma unroll
    for (int e = 0; e < QSPLIT; ++e) {
        p[e] = 0;
        hv[e] = hlv[base + e * KK];
        hj[e] = hlj[base + e * KK];
    }
    int* out = idxout + (size_t)row * KK;
    for (int r = 0; r < KK; ++r) {
        float bv = hv[0]; int bj = hj[0]; int L = 0;
        #pragma unroll
        for (int e = 1; e < QSPLIT; ++e) {
            bool bt = (hv[e] > bv) || (hv[e] == bv && hj[e] < bj);
            bv = bt ? hv[e] : bv; bj = bt ? hj[e] : bj; L = bt ? e : L;
        }
        out[r] = bj;
        #pragma unroll
        for (int e = 0; e < QSPLIT; ++e) {
            if (e == L) {
                ++p[e];
                bool ok = p[e] < KK;
                hv[e] = ok ? hlv[base + e * KK + p[e]] : -INFINITY;
                hj[e] = ok ? hlj[base + e * KK + p[e]] : 0x7fffffff;
            }
        }
    }
}

// ---------------- y,z = X*W1^T, X*W2^T as one tiled GEMM ----------------
__global__ __launch_bounds__(256) void yz_gemm_kernel(
    const float* __restrict__ x, const float* __restrict__ w,
    float* __restrict__ y, float* __restrict__ z, int C, int co) {
    int n0 = blockIdx.y << 6;     // point tile
    int oc0 = blockIdx.x << 6;    // combined output-channel tile
    __shared__ float As[16][68], Bs[16][68];
    int tid = threadIdx.x;
    int tx = tid & 15, ty = tid >> 4;
    float acc[4][4] = {};
    for (int k0 = 0; k0 < C; k0 += 16) {
        #pragma unroll
        for (int l = tid; l < 1024; l += 256) {
            int r = l >> 4, c = l & 15;
            int kc = k0 + c;
            As[c][r] = (kc < C) ? x[(size_t)(n0 + r) * C + kc] : 0.f;
            float bvv = 0.f;
            if (kc < C) {
                int oc = oc0 + r;
                int wrow = (oc < co) ? oc : (oc - co);
                int wcol = (oc < co) ? kc : (C + kc);
                bvv = w[(size_t)wrow * 2 * C + wcol];
            }
            Bs[c][r] = bvv;
        }
        __syncthreads();
        #pragma unroll
        for (int kk = 0; kk < 16; ++kk) {
            float4 a4 = *(const float4*)&As[kk][ty << 2];
            float4 b4 = *(const float4*)&Bs[kk][tx << 2];
            float a[4] = {a4.x, a4.y, a4.z, a4.w};
            float bv[4] = {b4.x, b4.y, b4.z, b4.w};
            #pragma unroll
            for (int u = 0; u < 4; ++u)
                #pragma unroll
                for (int v = 0; v < 4; ++v)
                    acc[u][v] = fmaf(a[u], bv[v], acc[u][v]);
        }
        __syncthreads();
    }
    bool isY = (oc0 < co);
    float* dst = isY ? y : z;
    int c0 = isY ? oc0 : (oc0 - co);
    #pragma unroll
    for (int u = 0; u < 4; ++u) {
        int n = n0 + (ty << 2) + u;
        float4 o;
        o.x = acc[u][0]; o.y = acc[u][1]; o.z = acc[u][2]; o.w = acc[u][3];
        *(float4*)&dst[(size_t)n * co + c0 + (tx << 2)] = o;
    }
}

// ---------------- gather + max_k + BN + lrelu ----------------
__global__ void edge_apply_kernel(const float* __restrict__ y, const float* __restrict__ z,
    const int* __restrict__ idx, const float* __restrict__ g, const float* __restrict__ be,
    const float* __restrict__ rm, const float* __restrict__ rv,
    float* __restrict__ out, int co) {
    int n = blockIdx.x;   // global point id in [0, B*N)
    int o = threadIdx.x;
    int b = n >> 11;      // N = 2048
    __shared__ int sj[KK];
    if (o < KK) sj[o] = idx[(size_t)n * KK + o];
    __syncthreads();
    float yn = y[(size_t)n * co + o], zn = z[(size_t)n * co + o];
    float mx = -INFINITY, mn = INFINITY;
    #pragma unroll
    for (int j = 0; j < KK; ++j) {
        float v = y[((size_t)b * NN + sj[j]) * co + o];
        mx = fmaxf(mx, v);
        mn = fminf(mn, v);
    }
    float s = g[o] * rsqrtf(rv[o] + EPSF);
    float tt = be[o] - rm[o] * s;
    float ybest = (s >= 0.f) ? mx : mn;
    float h = fmaf(s, ybest - yn + zn, tt);
    out[(size_t)n * co + o] = (h >= 0.f) ? h : NEG_SLOPE * h;
}

// ---------------- global max over N of concat(x1..x4) ----------------
#define NSPLIT 32
__global__ void gmax_partial(const float* __restrict__ x1, const float* __restrict__ x2,
                             const float* __restrict__ x3, const float* __restrict__ x4,
                             float* __restrict__ part) {
    int ch = threadIdx.x;            // 0..511
    int split = blockIdx.x, b = blockIdx.y;
    int n0 = split * (NN / NSPLIT);
    float m = -INFINITY;
    for (int q = 0; q < NN / NSPLIT; ++q) {
        int n = b * NN + n0 + q;
        float v;
        if (ch < 64)       v = x1[(size_t)n * 64 + ch];
        else if (ch < 128) v = x2[(size_t)n * 64 + (ch - 64)];
        else if (ch < 256) v = x3[(size_t)n * 128 + (ch - 128)];
        else               v = x4[(size_t)n * 256 + (ch - 256)];
        m = fmaxf(m, v);
    }
    part[((size_t)split * BB + b) * 512 + ch] = m;
}

__global__ void gmax_final(const float* __restrict__ part, float* __restrict__ xg) {
    int ch = threadIdx.x, b = blockIdx.x;
    float m = -INFINITY;
    for (int s = 0; s < NSPLIT; ++s) m = fmaxf(m, part[((size_t)s * BB + b) * 512 + ch]);
    xg[(size_t)b * 512 + ch] = m;
}

// ---------------- final linear + BN + lrelu ----------------
__global__ void linear_kernel(const float* __restrict__ xg, const float* __restrict__ lw,
    const float* __restrict__ lb, const float* __restrict__ g5, const float* __restrict__ b5,
    const float* __restrict__ rm5, const float* __restrict__ rv5, float* __restrict__ out0) {
    int o = blockIdx.x * 256 + threadIdx.x;
    int b = blockIdx.y;
    __shared__ float xs[512];
    for (int l = threadIdx.x; l < 512; l += 256) xs[l] = xg[(size_t)b * 512 + l];
    __syncthreads();
    float acc = 0.f;
    const float* wr = lw + (size_t)o * 512;
    for (int c = 0; c < 512; ++c) acc = fmaf(xs[c], wr[c], acc);
    acc += lb[o];
    float s = g5[o] * rsqrtf(rv5[o] + EPSF);
    float h = fmaf(s, acc - rm5[o], b5[o]);
    out0[(size_t)b * 1024 + o] = (h >= 0.f) ? h : NEG_SLOPE * h;
}

// ---------------- x4 (B,N,256) -> out1 (B,256,N) ----------------
__global__ void transpose_kernel(const float* __restrict__ x4, float* __restrict__ out1) {
    __shared__ float tile[32][33];
    int b = blockIdx.z;
    int nb = blockIdx.x * 32, ob = blockIdx.y * 32;
    int tx = threadIdx.x, ty = threadIdx.y;  // (32, 8)
    #pragma unroll
    for (int r = 0; r < 4; ++r) {
        int o = ob + tx;
        int n = nb + ty + r * 8;
        tile[ty + r * 8][tx] = x4[((size_t)b * NN + n) * 256 + o];
    }
    __syncthreads();
    #pragma unroll
    for (int r = 0; r < 4; ++r) {
        int n = nb + tx;
        int o = ob + ty + r * 8;
        out1[((size_t)b * 256 + o) * NN + n] = tile[tx][ty + r * 8];
    }
}

extern "C" void kernel_launch(void* const* d_in, const int* in_sizes, int n_in,
                              void* d_out, int out_size, void* d_ws, size_t ws_size,
                              hipStream_t stream) {
    const float* x = (const float*)d_in[0];
    const float* lin_w = (const float*)d_in[21];
    const float* lin_b = (const float*)d_in[22];
    const float* g5 = (const float*)d_in[23];
    const float* b5 = (const float*)d_in[24];
    const float* rm5 = (const float*)d_in[25];
    const float* rv5 = (const float*)d_in[26];

    // ---- workspace bump allocation ----
    size_t off = 0;
    auto alloc = [&](size_t nbytes) {
        void* r = (char*)d_ws + off;
        off += (nbytes + 255) & ~(size_t)255;
        return r;
    };
    const size_t PTS = (size_t)BB * NN;
    float* xx   = (float*)alloc(PTS * 4);
    int*   idx  = (int*)  alloc(PTS * KK * 4);
    float* y    = (float*)alloc(PTS * 256 * 4);
    float* z    = (float*)alloc(PTS * 256 * 4);
    float* x1   = (float*)alloc(PTS * 64 * 4);
    float* x2   = (float*)alloc(PTS * 64 * 4);
    float* x3   = (float*)alloc(PTS * 128 * 4);
    float* x4   = (float*)alloc(PTS * 256 * 4);
    float* part = (float*)alloc((size_t)NSPLIT * BB * 512 * 4);
    float* xg   = (float*)alloc((size_t)BB * 512 * 4);
    float* hlv  = (float*)alloc(PTS * QSPLIT * KK * 4);
    int*   hlj  = (int*)  alloc(PTS * QSPLIT * KK * 4);

    const int CI[4] = {5, 64, 64, 128};
    const int CO[4] = {64, 64, 128, 256};
    const float* xin = x;
    float* xout[4] = {x1, x2, x3, x4};

    for (int l = 0; l < 4; ++l) {
        int C = CI[l], co = CO[l];
        const float* w  = (const float*)d_in[1 + l * 5 + 0];
        const float* g  = (const float*)d_in[1 + l * 5 + 1];
        const float* be = (const float*)d_in[1 + l * 5 + 2];
        const float* rm = (const float*)d_in[1 + l * 5 + 3];
        const float* rv = (const float*)d_in[1 + l * 5 + 4];

        xx_kernel<<<(BB * NN + 255) / 256, 256, 0, stream>>>(xin, xx, C);
        knn_fused_kernel<<<dim3(QSPLIT, NN / 64, BB), 256, 0, stream>>>(xin, xx, hlv, hlj, C);
        topk_merge_kernel<<<(int)(PTS / 64), 64, 0, stream>>>(hlv, hlj, idx);

        yz_gemm_kernel<<<dim3(2 * co / 64, (int)(PTS / 64)), 256, 0, stream>>>(
            xin, w, y, z, C, co);
        edge_apply_kernel<<<(int)PTS, co, 0, stream>>>(y, z, idx, g, be, rm, rv, xout[l], co);
        xin = xout[l];
    }

    gmax_partial<<<dim3(NSPLIT, BB), 512, 0, stream>>>(x1, x2, x3, x4, part);
    gmax_final<<<BB, 512, 0, stream>>>(part, xg);
    linear_kernel<<<dim3(1024 / 256, BB), 256, 0, stream>>>(
        xg, lin_w, lin_b, g5, b5, rm5, rv5, (float*)d_out);
    transpose_kernel<<<dim3(NN / 32, 256 / 32, BB), dim3(32, 8), 0, stream>>>(
        x4, (float*)d_out + (size_t)BB * 1024);
}